// Round 7
// baseline (583.284 us; speedup 1.0000x reference)
//
#include <hip/hip_runtime.h>

typedef __bf16 bf16x8 __attribute__((ext_vector_type(8)));
typedef float  f32x4  __attribute__((ext_vector_type(4)));

#define TOKS 4096
#define DIM  1024
#define NEXP 8
#define NF   4096
#define CAP  4096   // per-expert pair capacity
#define BM 128
#define BN 128
#define BK 64

typedef __attribute__((address_space(3))) unsigned int as3_u32;
typedef __attribute__((address_space(1))) unsigned int as1_u32;
// async global->LDS, 16B per lane; LDS dest = wave-uniform base + lane*16
__device__ __forceinline__ void gl16(const unsigned short* g, unsigned short* l) {
  __builtin_amdgcn_global_load_lds((as1_u32*)(unsigned long long)g, (as3_u32*)l, 16, 0, 0);
}

__device__ __forceinline__ unsigned short f2bf(float f) {
  unsigned int u = __float_as_uint(f);
  u += 0x7FFFu + ((u >> 16) & 1u);           // round-to-nearest-even
  return (unsigned short)(u >> 16);
}
// fallback-kernel swizzle
__device__ __forceinline__ int swzo(int major) {
  return ((major & 7) ^ ((major >> 3) & 7)) << 3;
}
// XOR 16B-chunk index with row&7; arg/result in elements (8 bf16 chunks)
__device__ __forceinline__ int swz8(int row, int chunk) {
  return (chunk ^ (row & 7)) << 3;
}

// ---------------- routing ----------------
__global__ void moe_route(const float* __restrict__ x, const float* __restrict__ Wg,
                          int* __restrict__ pairCnt, int* __restrict__ pairIdx,
                          float* __restrict__ pairWgt, float* __restrict__ auxSum)
{
  int lane = threadIdx.x & 63;
  int tok  = blockIdx.x * 4 + (threadIdx.x >> 6);
  const float* xr = x + (size_t)tok * DIM;
  float acc[8];
  #pragma unroll
  for (int e = 0; e < 8; ++e) acc[e] = 0.f;
  #pragma unroll
  for (int i = 0; i < 16; ++i) {
    int d = i * 64 + lane;
    float xv = xr[d];
    const float4* wr = (const float4*)(Wg + d * 8);
    float4 wa = wr[0], wb = wr[1];
    acc[0] += xv * wa.x; acc[1] += xv * wa.y; acc[2] += xv * wa.z; acc[3] += xv * wa.w;
    acc[4] += xv * wb.x; acc[5] += xv * wb.y; acc[6] += xv * wb.z; acc[7] += xv * wb.w;
  }
  #pragma unroll
  for (int e = 0; e < 8; ++e) {
    float v = acc[e];
    #pragma unroll
    for (int off = 32; off; off >>= 1) v += __shfl_xor(v, off);
    acc[e] = v;
  }
  if (lane == 0) {
    int e1 = 0; float l1 = acc[0];
    #pragma unroll
    for (int e = 1; e < 8; ++e) if (acc[e] > l1) { l1 = acc[e]; e1 = e; }
    int e2 = -1; float l2 = -3.4e38f;
    #pragma unroll
    for (int e = 0; e < 8; ++e) if (e != e1 && acc[e] > l2) { l2 = acc[e]; e2 = e; }
    float r  = expf(l2 - l1);
    float w1 = 1.f / (1.f + r);
    float w2 = r / (1.f + r);
    int s1 = atomicAdd(&pairCnt[e1], 1);
    pairIdx[e1 * CAP + s1] = tok * 2;     pairWgt[e1 * CAP + s1] = w1;
    int s2 = atomicAdd(&pairCnt[e2], 1);
    pairIdx[e2 * CAP + s2] = tok * 2 + 1; pairWgt[e2 * CAP + s2] = w2;
    float m = 0.f;
    #pragma unroll
    for (int e = 0; e < 8; ++e) m += acc[e];
    m *= 0.125f;
    float v = 0.f;
    #pragma unroll
    for (int e = 0; e < 8; ++e) { float dd = acc[e] - m; v += dd * dd; }
    atomicAdd(auxSum, v * (1.f / 7.f));
  }
}

__global__ void moe_aux_final(const float* __restrict__ auxSum, float* __restrict__ outScalar) {
  *outScalar = auxSum[0] * (1.f / (float)TOKS);
}

// ---------------- x: fp32 -> bf16 ----------------
__global__ __launch_bounds__(256) void cvt_x(const float* __restrict__ in,
                                             unsigned short* __restrict__ o)
{
  int i = (blockIdx.x * 256 + threadIdx.x) * 16;
  const float4* s = (const float4*)(in + i);
  float4 a = s[0], b = s[1], c = s[2], d = s[3];
  union { unsigned short u[8]; uint4 q; } p0, p1;
  p0.u[0]=f2bf(a.x); p0.u[1]=f2bf(a.y); p0.u[2]=f2bf(a.z); p0.u[3]=f2bf(a.w);
  p0.u[4]=f2bf(b.x); p0.u[5]=f2bf(b.y); p0.u[6]=f2bf(b.z); p0.u[7]=f2bf(b.w);
  p1.u[0]=f2bf(c.x); p1.u[1]=f2bf(c.y); p1.u[2]=f2bf(c.z); p1.u[3]=f2bf(c.w);
  p1.u[4]=f2bf(d.x); p1.u[5]=f2bf(d.y); p1.u[6]=f2bf(d.z); p1.u[7]=f2bf(d.w);
  *(uint4*)(o + i)     = p0.q;
  *(uint4*)(o + i + 8) = p1.q;
}

// ---------------- weight prep: W2 fp32 [E][R][C] -> bf16 [E][C][R] ----------------
__global__ __launch_bounds__(256) void cvt_transpose(
    const float* __restrict__ in, unsigned short* __restrict__ outp, int R, int C)
{
  __shared__ unsigned short tile[64 * 72];
  int e  = blockIdx.z;
  int r0 = blockIdx.x * 64, c0 = blockIdx.y * 64;
  const float*    ine  = in   + (size_t)e * R * C;
  unsigned short* oute = outp + (size_t)e * R * C;
  int t = threadIdx.x;
  int r = t >> 2, cs = (t & 3) * 16;
  const float4* src = (const float4*)(ine + (size_t)(r0 + r) * C + c0 + cs);
  #pragma unroll
  for (int j = 0; j < 4; ++j) {
    float4 v = src[j];
    tile[(cs + j * 4 + 0) * 72 + r] = f2bf(v.x);
    tile[(cs + j * 4 + 1) * 72 + r] = f2bf(v.y);
    tile[(cs + j * 4 + 2) * 72 + r] = f2bf(v.z);
    tile[(cs + j * 4 + 3) * 72 + r] = f2bf(v.w);
  }
  __syncthreads();
  int c = t >> 2, rs = (t & 3) * 16;
  uint4 o0 = *(const uint4*)&tile[c * 72 + rs];
  uint4 o1 = *(const uint4*)&tile[c * 72 + rs + 8];
  unsigned short* dst = oute + (size_t)(c0 + c) * R + r0 + rs;
  *(uint4*)dst       = o0;
  *(uint4*)(dst + 8) = o1;
}

// ---------------- weight prep: W1,W3 fp32 [E][D][F] -> interleaved bf16 W13T ----------------
// W13T[e] has 2*NF rows of length DIM: row b*32 + w (w<16)  = W1 col b*16+w (transposed)
//                                      row b*32 + 16 + w    = W3 col b*16+w
__global__ __launch_bounds__(256) void cvt_w13(
    const float* __restrict__ W1, const float* __restrict__ W3,
    unsigned short* __restrict__ outp)
{
  __shared__ unsigned short t1[64 * 72];
  __shared__ unsigned short t3[64 * 72];
  int e  = blockIdx.z;
  int r0 = blockIdx.x * 64, c0 = blockIdx.y * 64;   // r0: D offset, c0: F offset
  const float* in1 = W1 + (size_t)e * DIM * NF;
  const float* in3 = W3 + (size_t)e * DIM * NF;
  unsigned short* oute = outp + (size_t)e * (2 * NF) * DIM;
  int t = threadIdx.x;
  int r = t >> 2, cs = (t & 3) * 16;
  const float4* s1 = (const float4*)(in1 + (size_t)(r0 + r) * NF + c0 + cs);
  const float4* s3 = (const float4*)(in3 + (size_t)(r0 + r) * NF + c0 + cs);
  #pragma unroll
  for (int j = 0; j < 4; ++j) {
    float4 v1 = s1[j];
    float4 v3 = s3[j];
    int cb = cs + j * 4;
    t1[(cb + 0) * 72 + r] = f2bf(v1.x);
    t1[(cb + 1) * 72 + r] = f2bf(v1.y);
    t1[(cb + 2) * 72 + r] = f2bf(v1.z);
    t1[(cb + 3) * 72 + r] = f2bf(v1.w);
    t3[(cb + 0) * 72 + r] = f2bf(v3.x);
    t3[(cb + 1) * 72 + r] = f2bf(v3.y);
    t3[(cb + 2) * 72 + r] = f2bf(v3.z);
    t3[(cb + 3) * 72 + r] = f2bf(v3.w);
  }
  __syncthreads();
  int c = t >> 2, rs = (t & 3) * 16;               // c: local f (0..63), rs: local d chunk
  int drow = c0 * 2 + (c >> 4) * 32 + (c & 15);    // interleaved dest row for W1
  uint4 a0 = *(const uint4*)&t1[c * 72 + rs];
  uint4 a1 = *(const uint4*)&t1[c * 72 + rs + 8];
  uint4 b0 = *(const uint4*)&t3[c * 72 + rs];
  uint4 b1 = *(const uint4*)&t3[c * 72 + rs + 8];
  unsigned short* d1 = oute + (size_t)drow * DIM + r0 + rs;
  unsigned short* d3 = d1 + (size_t)16 * DIM;
  *(uint4*)d1       = a0;
  *(uint4*)(d1 + 8) = a1;
  *(uint4*)d3       = b0;
  *(uint4*)(d3 + 8) = b1;
}

// ---------------- FFN1, 4-phase 256^2 schedule (T2+T3+T5), race-fixed ----------------
// Group j (reads buf CUR = tile j, stages tile j+1 into buf NXT):
//   P0: ds_read frags (KS=0,Q=0) | gl16 x4: A halves of tile j+1 | barrier | 16 MFMA
//   P1: ds_read (KS=0,Q=1)       | gl16 x4: B halves             | barrier | 16 MFMA
//   P2: ds_read (KS=1,Q=0)       | (no stage)                    | barrier | 16 MFMA
//   P3: ds_read (KS=1,Q=1) | lgkmcnt(0) + vmcnt(0) | barrier | 16 MFMA
// Hazard ledger:
//  - P0 gl16 into buf NXT vs reads of NXT (tile j-1): those reads drained via
//    lgkmcnt(0) before group j-1's P3 barrier -> safe.
//  - Next group's P0 ds_reads of buf NXT (tile j+1): vmcnt(0) before P3 barrier
//    guarantees every wave's 8 stage-loads landed; barrier makes it collective.
//  - Next group's P0 gl16 into buf CUR: all reads of CUR drained (lgkm(0)) before
//    P3 barrier -> safe. P3's MFMA after barrier uses registers only.
//  - vmcnt(0) at P3 is cheap: the 8 loads were issued at P0/P1, >= 2 phases earlier.
#define FFN1_PHASE(CUR, NXT, KS, Q, STG, DOWAIT, KTN) do {                       \
  int kc_ = (KS) * 4 + (lane >> 4);                                              \
  int sz_ = ((kc_ ^ (lane & 7)) << 3);                                           \
  int ar_ = wr * 128 + (Q) * 64 + (lane & 15);                                   \
  int br_ = wc * 64 + (lane & 15);                                               \
  bf16x8 a0_ = *(const bf16x8*)&As_[CUR][(ar_     ) * 64 + sz_];                 \
  bf16x8 a1_ = *(const bf16x8*)&As_[CUR][(ar_ + 16) * 64 + sz_];                 \
  bf16x8 a2_ = *(const bf16x8*)&As_[CUR][(ar_ + 32) * 64 + sz_];                 \
  bf16x8 a3_ = *(const bf16x8*)&As_[CUR][(ar_ + 48) * 64 + sz_];                 \
  bf16x8 b0_ = *(const bf16x8*)&Bs_[CUR][(br_     ) * 64 + sz_];                 \
  bf16x8 b1_ = *(const bf16x8*)&Bs_[CUR][(br_ + 16) * 64 + sz_];                 \
  bf16x8 b2_ = *(const bf16x8*)&Bs_[CUR][(br_ + 32) * 64 + sz_];                 \
  bf16x8 b3_ = *(const bf16x8*)&Bs_[CUR][(br_ + 48) * 64 + sz_];                 \
  if ((STG) == 1) {                                                              \
    gl16(pA[0][0] + (KTN), &As_[NXT][(w * 16      ) * 64]);                      \
    gl16(pA[0][1] + (KTN), &As_[NXT][(w * 16 +   8) * 64]);                      \
    gl16(pA[1][0] + (KTN), &As_[NXT][(w * 16 + 128) * 64]);                      \
    gl16(pA[1][1] + (KTN), &As_[NXT][(w * 16 + 136) * 64]);                      \
  } else if ((STG) == 2) {                                                       \
    gl16(pB[0][0] + (KTN), &Bs_[NXT][(w * 16      ) * 64]);                      \
    gl16(pB[0][1] + (KTN), &Bs_[NXT][(w * 16 +   8) * 64]);                      \
    gl16(pB[1][0] + (KTN), &Bs_[NXT][(w * 16 + 128) * 64]);                      \
    gl16(pB[1][1] + (KTN), &Bs_[NXT][(w * 16 + 136) * 64]);                      \
  }                                                                              \
  if (DOWAIT) {                                                                  \
    asm volatile("s_waitcnt lgkmcnt(0)" ::: "memory");                           \
    asm volatile("s_waitcnt vmcnt(0)" ::: "memory");                             \
  }                                                                              \
  __builtin_amdgcn_s_barrier();                                                  \
  __builtin_amdgcn_s_setprio(1);                                                 \
  acc[(Q)*4+0][0] = __builtin_amdgcn_mfma_f32_16x16x32_bf16(a0_, b0_, acc[(Q)*4+0][0], 0,0,0); \
  acc[(Q)*4+1][0] = __builtin_amdgcn_mfma_f32_16x16x32_bf16(a1_, b0_, acc[(Q)*4+1][0], 0,0,0); \
  acc[(Q)*4+2][0] = __builtin_amdgcn_mfma_f32_16x16x32_bf16(a2_, b0_, acc[(Q)*4+2][0], 0,0,0); \
  acc[(Q)*4+3][0] = __builtin_amdgcn_mfma_f32_16x16x32_bf16(a3_, b0_, acc[(Q)*4+3][0], 0,0,0); \
  acc[(Q)*4+0][1] = __builtin_amdgcn_mfma_f32_16x16x32_bf16(a0_, b1_, acc[(Q)*4+0][1], 0,0,0); \
  acc[(Q)*4+1][1] = __builtin_amdgcn_mfma_f32_16x16x32_bf16(a1_, b1_, acc[(Q)*4+1][1], 0,0,0); \
  acc[(Q)*4+2][1] = __builtin_amdgcn_mfma_f32_16x16x32_bf16(a2_, b1_, acc[(Q)*4+2][1], 0,0,0); \
  acc[(Q)*4+3][1] = __builtin_amdgcn_mfma_f32_16x16x32_bf16(a3_, b1_, acc[(Q)*4+3][1], 0,0,0); \
  acc[(Q)*4+0][2] = __builtin_amdgcn_mfma_f32_16x16x32_bf16(a0_, b2_, acc[(Q)*4+0][2], 0,0,0); \
  acc[(Q)*4+1][2] = __builtin_amdgcn_mfma_f32_16x16x32_bf16(a1_, b2_, acc[(Q)*4+1][2], 0,0,0); \
  acc[(Q)*4+2][2] = __builtin_amdgcn_mfma_f32_16x16x32_bf16(a2_, b2_, acc[(Q)*4+2][2], 0,0,0); \
  acc[(Q)*4+3][2] = __builtin_amdgcn_mfma_f32_16x16x32_bf16(a3_, b2_, acc[(Q)*4+3][2], 0,0,0); \
  acc[(Q)*4+0][3] = __builtin_amdgcn_mfma_f32_16x16x32_bf16(a0_, b3_, acc[(Q)*4+0][3], 0,0,0); \
  acc[(Q)*4+1][3] = __builtin_amdgcn_mfma_f32_16x16x32_bf16(a1_, b3_, acc[(Q)*4+1][3], 0,0,0); \
  acc[(Q)*4+2][3] = __builtin_amdgcn_mfma_f32_16x16x32_bf16(a2_, b3_, acc[(Q)*4+2][3], 0,0,0); \
  acc[(Q)*4+3][3] = __builtin_amdgcn_mfma_f32_16x16x32_bf16(a3_, b3_, acc[(Q)*4+3][3], 0,0,0); \
  __builtin_amdgcn_s_setprio(0);                                                 \
} while (0)

#define FFN1_GROUP(CUR, NXT, KTN)           \
  FFN1_PHASE(CUR, NXT, 0, 0, 1, 0, KTN);    \
  FFN1_PHASE(CUR, NXT, 0, 1, 2, 0, KTN);    \
  FFN1_PHASE(CUR, NXT, 1, 0, 0, 0, KTN);    \
  FFN1_PHASE(CUR, NXT, 1, 1, 0, 1, KTN);

__global__ __launch_bounds__(512, 2) void moe_ffn1_8p(
    const unsigned short* __restrict__ xbf, const unsigned short* __restrict__ W13T,
    const int* __restrict__ pairCnt, const int* __restrict__ pairIdx,
    unsigned short* __restrict__ hbuf)
{
  // bid bits: [0:3)=n_low(XCD), [3:7)=m (16), [7:9)=n_high, [9:12)=e
  int bid = blockIdx.x;
  int n_t = (bid & 7) | (((bid >> 7) & 3) << 3);   // 0..31
  int m_t = (bid >> 3) & 15;
  int e   = bid >> 9;
  int cnt = pairCnt[e];
  int m0  = m_t * 256;
  if (m0 >= cnt) return;
  __shared__ __attribute__((aligned(16))) unsigned short As_[2][256 * 64];
  __shared__ __attribute__((aligned(16))) unsigned short Bs_[2][256 * 64];
  __shared__ int rowPid[256];
  int tid = threadIdx.x, lane = tid & 63, w = tid >> 6;
  if (tid < 256) {
    int gi = m0 + tid;
    rowPid[tid] = (gi < cnt) ? pairIdx[e * CAP + gi] : -1;
  }
  const unsigned short* W13e = W13T + (size_t)e * (2 * NF) * DIM + (size_t)n_t * 256 * DIM;
  int wr = w >> 2, wc = w & 3;
  f32x4 zero = {0.f, 0.f, 0.f, 0.f};
  f32x4 acc[8][4];
  #pragma unroll
  for (int mi = 0; mi < 8; ++mi)
    #pragma unroll
    for (int ni = 0; ni < 4; ++ni) acc[mi][ni] = zero;
  __syncthreads();   // rowPid visible

  // staging sources: wave w stages rows h*128 + w*16 + {0..15} (per half h)
  int sr = w * 16 + (lane >> 3);                  // row within half, k=0 slice
  int sc = ((lane & 7) ^ (lane >> 3)) * 8;        // pre-swizzled source chunk (elements)
  const unsigned short* pA[2][2];
  const unsigned short* pB[2][2];
  #pragma unroll
  for (int h = 0; h < 2; ++h) {
    #pragma unroll
    for (int k = 0; k < 2; ++k) {
      int R = h * 128 + sr + k * 8;
      int pid = rowPid[R];
      pA[h][k] = xbf + (size_t)((pid >= 0) ? (pid >> 1) : 0) * DIM + sc;
      pB[h][k] = W13e + (size_t)R * DIM + sc;
    }
  }
  // prologue: stage K-tile 0 into buf0 (8 gl16), then DRAIN before first reads
  gl16(pA[0][0], &As_[0][(w * 16      ) * 64]);
  gl16(pA[0][1], &As_[0][(w * 16 +   8) * 64]);
  gl16(pA[1][0], &As_[0][(w * 16 + 128) * 64]);
  gl16(pA[1][1], &As_[0][(w * 16 + 136) * 64]);
  gl16(pB[0][0], &Bs_[0][(w * 16      ) * 64]);
  gl16(pB[0][1], &Bs_[0][(w * 16 +   8) * 64]);
  gl16(pB[1][0], &Bs_[0][(w * 16 + 128) * 64]);
  gl16(pB[1][1], &Bs_[0][(w * 16 + 136) * 64]);
  asm volatile("s_waitcnt vmcnt(0)" ::: "memory");
  __builtin_amdgcn_s_barrier();

  for (int j = 0; j < 16; j += 2) {
    int ktn0 = (j + 1) * 64;
    int ktn1 = (j + 2 < 16) ? (j + 2) * 64 : (j + 1) * 64;   // last: re-stage (L2-hit, harmless)
    FFN1_GROUP(0, 1, ktn0);
    FFN1_GROUP(1, 0, ktn1);
  }

  // epilogue: ni = fg*2 -> a (W1), fg*2+1 -> g (W3); same f column, same lane
  #pragma unroll
  for (int mi = 0; mi < 8; ++mi) {
    #pragma unroll
    for (int r = 0; r < 4; ++r) {
      int row = wr * 128 + mi * 16 + ((lane >> 4) << 2) + r;
      int pid = rowPid[row];
      if (pid < 0) continue;
      size_t hb = (size_t)pid * NF + n_t * 128 + wc * 32 + (lane & 15);
      #pragma unroll
      for (int fg = 0; fg < 2; ++fg) {
        float a = acc[mi][fg * 2 + 0][r];
        float g = acc[mi][fg * 2 + 1][r];
        float s = 1.f / (1.f + __expf(-a));
        hbuf[hb + fg * 16] = f2bf(a * s * g);
      }
    }
  }
}

// ---------------- FFN2 (global_load_lds staging, 2-phase): out[tok] += w * (h @ W2) ----------------
__global__ __launch_bounds__(512) void moe_ffn2_g(
    const unsigned short* __restrict__ hbuf, const unsigned short* __restrict__ W2T,
    const int* __restrict__ pairCnt, const int* __restrict__ pairIdx,
    const float* __restrict__ pairWgt, float* __restrict__ out)
{
  // bid bits: [0:3)=n(XCD), [3:8)=m, [8:11)=e
  int bid = blockIdx.x;
  int n_t = bid & 7;
  int m_t = (bid >> 3) & 31;
  int e   = bid >> 8;
  int cnt = pairCnt[e];
  int m0  = m_t * BM;
  if (m0 >= cnt) return;
  int n0  = n_t * BN;
  __shared__ __attribute__((aligned(16))) unsigned short As[BM * BK];
  __shared__ __attribute__((aligned(16))) unsigned short Bs[BN * BK];
  __shared__ int   rowPid[BM];
  __shared__ float rowW[BM];
  int tid = threadIdx.x, lane = tid & 63, wid = tid >> 6;
  if (tid < BM) {
    int gi = m0 + tid;
    if (gi < cnt) { rowPid[tid] = pairIdx[e * CAP + gi]; rowW[tid] = pairWgt[e * CAP + gi]; }
    else          { rowPid[tid] = -1;                    rowW[tid] = 0.f; }
  }
  const unsigned short* W2e = W2T + (size_t)e * DIM * NF + (size_t)n0 * NF;
  f32x4 zero = {0.f, 0.f, 0.f, 0.f};
  f32x4 acc[2][4];
  #pragma unroll
  for (int mi = 0; mi < 2; ++mi)
    #pragma unroll
    for (int ni = 0; ni < 4; ++ni) acc[mi][ni] = zero;
  int wm = (wid >> 1) * 32, wn = (wid & 1) * 64;
  __syncthreads();

  int r0a = wid * 16 + (lane >> 3), r1a = r0a + 8;
  int p0 = rowPid[r0a], p1 = rowPid[r1a];
  size_t h0 = (size_t)((p0 >= 0) ? p0 : 0);
  size_t h1 = (size_t)((p1 >= 0) ? p1 : 0);
  int ch0 = ((lane & 7) ^ (r0a & 7)) * 8;
  int ch1 = ((lane & 7) ^ (r1a & 7)) * 8;
  const unsigned short* gA0 = hbuf + h0 * NF + ch0;
  const unsigned short* gA1 = hbuf + h1 * NF + ch1;
  const unsigned short* gB0 = W2e + (size_t)r0a * NF + ch0;
  const unsigned short* gB1 = W2e + (size_t)r1a * NF + ch1;
  unsigned short* lA0 = &As[(wid * 16) * BK];
  unsigned short* lA1 = &As[(wid * 16 + 8) * BK];
  unsigned short* lB0 = &Bs[(wid * 16) * BK];
  unsigned short* lB1 = &Bs[(wid * 16 + 8) * BK];

  for (int kt = 0; kt < NF; kt += BK) {
    gl16(gA0 + kt, lA0); gl16(gA1 + kt, lA1);
    gl16(gB0 + kt, lB0); gl16(gB1 + kt, lB1);
    __syncthreads();
    #pragma unroll
    for (int ks = 0; ks < 2; ++ks) {
      int kc = ks * 4 + (lane >> 4);
      bf16x8 af[2];
      #pragma unroll
      for (int mi = 0; mi < 2; ++mi) {
        int row = wm + mi * 16 + (lane & 15);
        af[mi] = *(const bf16x8*)(&As[row * BK + swz8(row, kc)]);
      }
      #pragma unroll
      for (int ni = 0; ni < 4; ++ni) {
        int dc = wn + ni * 16 + (lane & 15);
        bf16x8 b = *(const bf16x8*)(&Bs[dc * BK + swz8(dc, kc)]);
        #pragma unroll
        for (int mi = 0; mi < 2; ++mi)
          acc[mi][ni] = __builtin_amdgcn_mfma_f32_16x16x32_bf16(af[mi], b, acc[mi][ni], 0, 0, 0);
      }
    }
    __syncthreads();
  }
  #pragma unroll
  for (int mi = 0; mi < 2; ++mi) {
    #pragma unroll
    for (int r = 0; r < 4; ++r) {
      int row = wm + mi * 16 + ((lane >> 4) << 2) + r;
      int pid = rowPid[row];
      if (pid < 0) continue;
      float w = rowW[row];
      float* op = out + (size_t)(pid >> 1) * DIM + n0 + wn + (lane & 15);
      #pragma unroll
      for (int ni = 0; ni < 4; ++ni)
        atomicAdd(op + ni * 16, w * acc[mi][ni][r]);
    }
  }
}

// ================= fallback (fp32 weights in-kernel, small ws) =================
__global__ __launch_bounds__(512) void moe_ffn1(
    const float* __restrict__ x, const float* __restrict__ W1, const float* __restrict__ W3,
    const int* __restrict__ pairCnt, const int* __restrict__ pairIdx,
    unsigned short* __restrict__ hbuf)
{
  int e   = blockIdx.z;
  int cnt = pairCnt[e];
  int m0  = blockIdx.x * BM;
  if (m0 >= cnt) return;
  int n0  = blockIdx.y * BN;
  __shared__ __attribute__((aligned(16))) unsigned short As[BM * BK];
  __shared__ __attribute__((aligned(16))) unsigned short B1s[BN * BK];
  __shared__ __attribute__((aligned(16))) unsigned short B3s[BN * BK];
  __shared__ int rowPid[BM];
  int tid = threadIdx.x;
  if (tid < BM) {
    int gi = m0 + tid;
    rowPid[tid] = (gi < cnt) ? pairIdx[e * CAP + gi] : -1;
  }
  const float* W1e = W1 + (size_t)e * DIM * NF;
  const float* W3e = W3 + (size_t)e * DIM * NF;
  f32x4 zero = {0.f, 0.f, 0.f, 0.f};
  f32x4 acc1[2][4], acc2[2][4];
  #pragma unroll
  for (int mi = 0; mi < 2; ++mi)
    #pragma unroll
    for (int ni = 0; ni < 4; ++ni) { acc1[mi][ni] = zero; acc2[mi][ni] = zero; }
  int lane = tid & 63, wid = tid >> 6;
  int wm = (wid >> 1) * 32, wn = (wid & 1) * 64;

  for (int kt = 0; kt < DIM; kt += BK) {
    __syncthreads();
    #pragma unroll
    for (int it = 0; it < 4; ++it) {
      int row = it * 32 + (tid >> 4);
      int dq  = tid & 15;
      int pid = rowPid[row];
      int tk  = (pid >= 0) ? (pid >> 1) : 0;
      float4 v = *(const float4*)(x + (size_t)tk * DIM + kt + dq * 4);
      ushort4 b; b.x = f2bf(v.x); b.y = f2bf(v.y); b.z = f2bf(v.z); b.w = f2bf(v.w);
      *(ushort4*)(&As[row * BK + ((dq * 4) ^ swzo(row))]) = b;
    }
    #pragma unroll
    for (int it = 0; it < 4; ++it) {
      int d  = it * 16 + (tid >> 5);
      int fq = tid & 31;
      size_t go = (size_t)(kt + d) * NF + n0 + fq * 4;
      float4 v1 = *(const float4*)(W1e + go);
      float4 v3 = *(const float4*)(W3e + go);
      const float* p1 = (const float*)&v1;
      const float* p3 = (const float*)&v3;
      #pragma unroll
      for (int i = 0; i < 4; ++i) {
        int f   = fq * 4 + i;
        int idx = f * BK + (d ^ swzo(f));
        B1s[idx] = f2bf(p1[i]);
        B3s[idx] = f2bf(p3[i]);
      }
    }
    __syncthreads();
    #pragma unroll
    for (int ks = 0; ks < 2; ++ks) {
      int kb = ks * 32 + ((lane >> 4) << 3);
      bf16x8 af[2];
      #pragma unroll
      for (int mi = 0; mi < 2; ++mi) {
        int row = wm + mi * 16 + (lane & 15);
        af[mi] = *(const bf16x8*)(&As[row * BK + (kb ^ swzo(row))]);
      }
      #pragma unroll
      for (int ni = 0; ni < 4; ++ni) {
        int f = wn + ni * 16 + (lane & 15);
        bf16x8 b1 = *(const bf16x8*)(&B1s[f * BK + (kb ^ swzo(f))]);
        bf16x8 b3 = *(const bf16x8*)(&B3s[f * BK + (kb ^ swzo(f))]);
        #pragma unroll
        for (int mi = 0; mi < 2; ++mi) {
          acc1[mi][ni] = __builtin_amdgcn_mfma_f32_16x16x32_bf16(af[mi], b1, acc1[mi][ni], 0, 0, 0);
          acc2[mi][ni] = __builtin_amdgcn_mfma_f32_16x16x32_bf16(af[mi], b3, acc2[mi][ni], 0, 0, 0);
        }
      }
    }
  }
  #pragma unroll
  for (int mi = 0; mi < 2; ++mi) {
    #pragma unroll
    for (int r = 0; r < 4; ++r) {
      int row = wm + mi * 16 + ((lane >> 4) << 2) + r;
      int pid = rowPid[row];
      if (pid < 0) continue;
      size_t hb = (size_t)pid * NF + n0 + wn + (lane & 15);
      #pragma unroll
      for (int ni = 0; ni < 4; ++ni) {
        float a = acc1[mi][ni][r];
        float g = acc2[mi][ni][r];
        float s = 1.f / (1.f + __expf(-a));
        hbuf[hb + ni * 16] = f2bf(a * s * g);
      }
    }
  }
}

__global__ __launch_bounds__(512) void moe_ffn2(
    const unsigned short* __restrict__ hbuf, const float* __restrict__ W2,
    const int* __restrict__ pairCnt, const int* __restrict__ pairIdx,
    const float* __restrict__ pairWgt, float* __restrict__ out)
{
  int e   = blockIdx.z;
  int cnt = pairCnt[e];
  int m0  = blockIdx.x * BM;
  if (m0 >= cnt) return;
  int n0  = blockIdx.y * BN;
  __shared__ __attribute__((aligned(16))) unsigned short As[BM * BK];
  __shared__ __attribute__((aligned(16))) unsigned short Bs[BN * BK];
  __shared__ int   rowPid[BM];
  __shared__ float rowW[BM];
  int tid = threadIdx.x;
  if (tid < BM) {
    int gi = m0 + tid;
    if (gi < cnt) { rowPid[tid] = pairIdx[e * CAP + gi]; rowW[tid] = pairWgt[e * CAP + gi]; }
    else          { rowPid[tid] = -1;                    rowW[tid] = 0.f; }
  }
  const float* W2e = W2 + (size_t)e * NF * DIM;
  f32x4 zero = {0.f, 0.f, 0.f, 0.f};
  f32x4 acc[2][4];
  #pragma unroll
  for (int mi = 0; mi < 2; ++mi)
    #pragma unroll
    for (int ni = 0; ni < 4; ++ni) acc[mi][ni] = zero;
  int lane = tid & 63, wid = tid >> 6;
  int wm = (wid >> 1) * 32, wn = (wid & 1) * 64;

  for (int kt = 0; kt < NF; kt += BK) {
    __syncthreads();
    #pragma unroll
    for (int it = 0; it < 2; ++it) {
      int row = it * 64 + (tid >> 3);
      int c8  = tid & 7;
      int pid = rowPid[row];
      int pr  = (pid >= 0) ? pid : 0;
      uint4 v = *(const uint4*)(hbuf + (size_t)pr * NF + kt + c8 * 8);
      *(uint4*)(&As[row * BK + ((c8 * 8) ^ swzo(row))]) = v;
    }
    #pragma unroll
    for (int it = 0; it < 4; ++it) {
      int fk = it * 16 + (tid >> 5);
      int dq = tid & 31;
      float4 v = *(const float4*)(W2e + (size_t)(kt + fk) * DIM + n0 + dq * 4);
      const float* p = (const float*)&v;
      #pragma unroll
      for (int i = 0; i < 4; ++i) {
        int dc = dq * 4 + i;
        Bs[dc * BK + (fk ^ swzo(dc))] = f2bf(p[i]);
      }
    }
    __syncthreads();
    #pragma unroll
    for (int ks = 0; ks < 2; ++ks) {
      int kb = ks * 32 + ((lane >> 4) << 3);
      bf16x8 af[2];
      #pragma unroll
      for (int mi = 0; mi < 2; ++mi) {
        int row = wm + mi * 16 + (lane & 15);
        af[mi] = *(const bf16x8*)(&As[row * BK + (kb ^ swzo(row))]);
      }
      #pragma unroll
      for (int ni = 0; ni < 4; ++ni) {
        int dc = wn + ni * 16 + (lane & 15);
        bf16x8 b = *(const bf16x8*)(&Bs[dc * BK + (kb ^ swzo(dc))]);
        #pragma unroll
        for (int mi = 0; mi < 2; ++mi)
          acc[mi][ni] = __builtin_amdgcn_mfma_f32_16x16x32_bf16(af[mi], b, acc[mi][ni], 0, 0, 0);
      }
    }
  }
  #pragma unroll
  for (int mi = 0; mi < 2; ++mi) {
    #pragma unroll
    for (int r = 0; r < 4; ++r) {
      int row = wm + mi * 16 + ((lane >> 4) << 2) + r;
      int pid = rowPid[row];
      if (pid < 0) continue;
      float w = rowW[row];
      float* op = out + (size_t)(pid >> 1) * DIM + n0 + wn + (lane & 15);
      #pragma unroll
      for (int ni = 0; ni < 4; ++ni)
        atomicAdd(op + ni * 16, w * acc[mi][ni][r]);
    }
  }
}

extern "C" void kernel_launch(void* const* d_in, const int* in_sizes, int n_in,
                              void* d_out, int out_size, void* d_ws, size_t ws_size,
                              hipStream_t stream)
{
  const float* x  = (const float*)d_in[0];
  const float* Wg = (const float*)d_in[1];
  const float* W1 = (const float*)d_in[2];
  const float* W2 = (const float*)d_in[3];
  const float* W3 = (const float*)d_in[4];
  float* out = (float*)d_out;
  char*  ws  = (char*)d_ws;
  int*   pairCnt = (int*)ws;
  float* auxSum  = (float*)(ws + 64);
  int*   pairIdx = (int*)(ws + 4096);
  float* pairWgt = (float*)(ws + 262144);
  // fast-path layout (from 1 MiB): xbf 8M, hbuf 64M, W13T 128M, W2T 64M
  unsigned short* xbf  = (unsigned short*)(ws + ((size_t)1 << 20));
  unsigned short* hbuf = (unsigned short*)(ws + ((size_t)9 << 20));
  unsigned short* W13T = (unsigned short*)(ws + ((size_t)73 << 20));
  unsigned short* W2T  = (unsigned short*)(ws + ((size_t)201 << 20));
  const size_t WS_NEED = (size_t)265 << 20;

  hipMemsetAsync(ws, 0, 128, stream);
  hipMemsetAsync(d_out, 0, (size_t)out_size * sizeof(float), stream);
  moe_route<<<TOKS / 4, 256, 0, stream>>>(x, Wg, pairCnt, pairIdx, pairWgt, auxSum);
  moe_aux_final<<<1, 1, 0, stream>>>(auxSum, out + (out_size - 1));

  if (ws_size >= WS_NEED) {
    cvt_x<<<TOKS * DIM / (256 * 16), 256, 0, stream>>>(x, xbf);
    cvt_w13<<<dim3(DIM / 64, NF / 64, NEXP), 256, 0, stream>>>(W1, W3, W13T);
    cvt_transpose<<<dim3(NF / 64, DIM / 64, NEXP), 256, 0, stream>>>(W2, W2T, NF, DIM);
    moe_ffn1_8p<<<16 * 32 * NEXP, 512, 0, stream>>>(xbf, W13T, pairCnt, pairIdx, hbuf);
    moe_ffn2_g<<<(TOKS / BM) * (DIM / BN) * NEXP, 512, 0, stream>>>(hbuf, W2T, pairCnt, pairIdx, pairWgt, out);
  } else {
    moe_ffn1<<<dim3(TOKS / BM, NF / BN, NEXP), 512, 0, stream>>>(x, W1, W3, pairCnt, pairIdx, hbuf);
    moe_ffn2<<<dim3(TOKS / BM, DIM / BN, NEXP), 512, 0, stream>>>(hbuf, W2, pairCnt, pairIdx, pairWgt, out);
  }
}